// Round 2
// baseline (567.586 us; speedup 1.0000x reference)
//
#include <hip/hip_runtime.h>

namespace {

constexpr int   IMG = 512;
constexpr float THR = 50.0f / 255.0f;

__global__ void zero_acc_kernel(double* __restrict__ acc) {
  if (threadIdx.x < 5) acc[threadIdx.x] = 0.0;
}

// Tile: 32x32 output pixels per block, 256 threads.
// jax.image.resize 'linear' 256->512 closed form (with index clamp making the
// interior formula exact at boundaries, verified bit-exact in R1):
//   even g=2k: 0.25*in[k-1] + 0.75*in[k];  odd g=2k+1: 0.75*in[k] + 0.25*in[k+1]
__global__ __launch_bounds__(256, 6) void n2n_wavelet_kernel(
    const float* __restrict__ noisy,
    const float* __restrict__ weight,
    double* __restrict__ acc) {
  __shared__ float sP0[18][20];   // p0 = noisy[0::2,0::2] window, clamped
  __shared__ float sP3[18][20];   // p3 = noisy[1::2,1::2] window, clamped
  __shared__ float sG1[34][36];   // g1 tile + conv halo (zero outside image)
  __shared__ float sOut[32][36];  // clipped conv output
  __shared__ float sLL1[16][18];
  __shared__ float sLL2[8][10];
  __shared__ float sRed[4][5];

  const int t  = threadIdx.x;
  const int tx = blockIdx.x;
  const int ty = blockIdx.y;
  const int b  = blockIdx.z;
  const float* img = noisy + (size_t)b * IMG * IMG;

  const int py0 = 16 * ty - 1;  // staging origin in p0/p3 index space
  const int px0 = 16 * tx - 1;

  float wk[9];
#pragma unroll
  for (int i = 0; i < 9; ++i) wk[i] = weight[i];

  // ---- Phase A: stage 18x18 p0 and p3 windows (clamped) ----
  {
    const int r = t >> 4, c = t & 15;
    auto stage = [&](int rr, int cc) {
      int gr = py0 + rr; gr = gr < 0 ? 0 : (gr > 255 ? 255 : gr);
      int gc = px0 + cc; gc = gc < 0 ? 0 : (gc > 255 ? 255 : gc);
      sP0[rr][cc] = img[(gr * 2) * IMG + gc * 2];
      sP3[rr][cc] = img[(gr * 2 + 1) * IMG + gc * 2 + 1];
    };
    stage(r, c);
    if (c < 2) stage(r, c + 16);
    if (r < 2) stage(r + 16, c);
    if (r < 2 && c < 2) stage(r + 16, c + 16);
  }
  __syncthreads();

  const int gyb0 = 32 * ty, gxb0 = 32 * tx;

  // ---- Phase B: g1 via 2x2 quads (pair-factored bilinear), 17x17 quads ----
  for (int q = t; q < 289; q += 256) {
    const int n = q / 17;          // compile-time magic mul
    const int m = q - n * 17;
    const float a  = sP0[n][m],     bb = sP0[n][m + 1];
    const float cc = sP0[n + 1][m], dd = sP0[n + 1][m + 1];
    const float xt0 = 0.75f * a + 0.25f * bb;   // local col 2m   (odd gx)
    const float xt1 = 0.25f * a + 0.75f * bb;   // local col 2m+1 (even gx)
    const float xb0 = 0.75f * cc + 0.25f * dd;
    const float xb1 = 0.25f * cc + 0.75f * dd;
    float v00 = 0.75f * xt0 + 0.25f * xb0;      // local row 2n   (odd gy)
    float v01 = 0.75f * xt1 + 0.25f * xb1;
    float v10 = 0.25f * xt0 + 0.75f * xb0;      // local row 2n+1 (even gy)
    float v11 = 0.25f * xt1 + 0.75f * xb1;
    // SAME-pad: zero outside image (only edge tiles hit this)
    const int gyt = gyb0 - 1 + 2 * n, gxl = gxb0 - 1 + 2 * m;
    const bool vt = (unsigned)gyt < (unsigned)IMG, vb = (unsigned)(gyt + 1) < (unsigned)IMG;
    const bool vl = (unsigned)gxl < (unsigned)IMG, vr = (unsigned)(gxl + 1) < (unsigned)IMG;
    v00 = (vt && vl) ? v00 : 0.0f;  v01 = (vt && vr) ? v01 : 0.0f;
    v10 = (vb && vl) ? v10 : 0.0f;  v11 = (vb && vr) ? v11 : 0.0f;
    *(float2*)&sG1[2 * n][2 * m]     = make_float2(v00, v01);
    *(float2*)&sG1[2 * n + 1][2 * m] = make_float2(v10, v11);
  }
  __syncthreads();

  // ---- Phase C: conv3x3 + clip + rec/reg; thread = 1 row x 4 cols ----
  float rec = 0.0f, rgg = 0.0f;
  {
    const int row  = t >> 3;          // 0..31
    const int col0 = (t & 7) << 2;    // 0..28 step 4
    float a0 = 0, a1 = 0, a2 = 0, a3 = 0;
    float g1c0 = 0, g1c1 = 0, g1c2 = 0, g1c3 = 0;
#pragma unroll
    for (int u = 0; u < 3; ++u) {
      const float4 q4 = *(const float4*)&sG1[row + u][col0];      // 16B aligned
      const float2 e2 = *(const float2*)&sG1[row + u][col0 + 4];  // 8B aligned
      const float w0 = wk[3 * u], w1 = wk[3 * u + 1], w2 = wk[3 * u + 2];
      a0 += w0 * q4.x + w1 * q4.y + w2 * q4.z;
      a1 += w0 * q4.y + w1 * q4.z + w2 * q4.w;
      a2 += w0 * q4.z + w1 * q4.w + w2 * e2.x;
      a3 += w0 * q4.w + w1 * e2.x + w2 * e2.y;
      if (u == 1) { g1c0 = q4.y; g1c1 = q4.z; g1c2 = q4.w; g1c3 = e2.x; }
    }
    const float o0 = fminf(fmaxf(a0, 0.0f), 1.0f);
    const float o1 = fminf(fmaxf(a1, 0.0f), 1.0f);
    const float o2 = fminf(fmaxf(a2, 0.0f), 1.0f);
    const float o3 = fminf(fmaxf(a3, 0.0f), 1.0f);
    *(float4*)&sOut[row][col0] = make_float4(o0, o1, o2, o3);

    // g2 taps from sP3
    const int   r0l = (row >> 1) + (row & 1);
    const float wyt = (row & 1) ? 0.75f : 0.25f;
    const float wyb = 1.0f - wyt;
    const int   c0l = col0 >> 1;
    const float2 t01 = *(const float2*)&sP3[r0l][c0l];
    const float2 t23 = *(const float2*)&sP3[r0l][c0l + 2];
    const float2 b01 = *(const float2*)&sP3[r0l + 1][c0l];
    const float2 b23 = *(const float2*)&sP3[r0l + 1][c0l + 2];
    const float xt0 = 0.25f * t01.x + 0.75f * t01.y;
    const float xt1 = 0.75f * t01.y + 0.25f * t23.x;
    const float xt2 = 0.25f * t01.y + 0.75f * t23.x;
    const float xt3 = 0.75f * t23.x + 0.25f * t23.y;
    const float xb0 = 0.25f * b01.x + 0.75f * b01.y;
    const float xb1 = 0.75f * b01.y + 0.25f * b23.x;
    const float xb2 = 0.25f * b01.y + 0.75f * b23.x;
    const float xb3 = 0.75f * b23.x + 0.25f * b23.y;
    const float g20 = wyt * xt0 + wyb * xb0;
    const float g21 = wyt * xt1 + wyb * xb1;
    const float g22 = wyt * xt2 + wyb * xb2;
    const float g23 = wyt * xt3 + wyb * xb3;

    float d;
    d = o0 - g20; rec += d * d;   d = o1 - g21; rec += d * d;
    d = o2 - g22; rec += d * d;   d = o3 - g23; rec += d * d;
    d = o0 - g1c0; rgg += d * d;  d = o1 - g1c1; rgg += d * d;
    d = o2 - g1c2; rgg += d * d;  d = o3 - g1c3; rgg += d * d;
  }
  __syncthreads();

  // ---- Phase D: 3-level Haar ----
  float w1a = 0.0f, w2a = 0.0f, w3a = 0.0f;
  {
    const int i = t >> 4, j = t & 15;   // 16x16: one coeff per thread
    const float2 top = *(const float2*)&sOut[2 * i][2 * j];
    const float2 bot = *(const float2*)&sOut[2 * i + 1][2 * j];
    const float aa = top.x, bb = top.y, cc = bot.x, dd = bot.y;
    sLL1[i][j] = (aa + bb + cc + dd) * 0.5f;
    const float lh = (aa - bb + cc - dd) * 0.5f;
    const float hl = (aa + bb - cc - dd) * 0.5f;
    const float hh = (aa - bb - cc + dd) * 0.5f;
    const float th = THR * 0.25f;
    w1a = fminf(fabsf(lh), th) + fminf(fabsf(hl), th) + fminf(fabsf(hh), th);
  }
  __syncthreads();
  if (t < 64) {
    const int i = t >> 3, j = t & 7;    // 8x8
    const float2 top = *(const float2*)&sLL1[2 * i][2 * j];
    const float2 bot = *(const float2*)&sLL1[2 * i + 1][2 * j];
    const float aa = top.x, bb = top.y, cc = bot.x, dd = bot.y;
    sLL2[i][j] = (aa + bb + cc + dd) * 0.5f;
    const float lh = (aa - bb + cc - dd) * 0.5f;
    const float hl = (aa + bb - cc - dd) * 0.5f;
    const float hh = (aa - bb - cc + dd) * 0.5f;
    const float th = THR * 0.5f;
    w2a = fminf(fabsf(lh), th) + fminf(fabsf(hl), th) + fminf(fabsf(hh), th);
  }
  __syncthreads();
  if (t < 16) {
    const int i = t >> 2, j = t & 3;    // 4x4
    const float2 top = *(const float2*)&sLL2[2 * i][2 * j];
    const float2 bot = *(const float2*)&sLL2[2 * i + 1][2 * j];
    const float aa = top.x, bb = top.y, cc = bot.x, dd = bot.y;
    const float lh = (aa - bb + cc - dd) * 0.5f;
    const float hl = (aa + bb - cc - dd) * 0.5f;
    const float hh = (aa - bb - cc + dd) * 0.5f;
    w3a = fminf(fabsf(lh), THR) + fminf(fabsf(hl), THR) + fminf(fabsf(hh), THR);
  }

  // ---- Block reduce 5 sums -> 5 double atomics ----
  float vals[5] = {rec, rgg, w1a, w2a, w3a};
#pragma unroll
  for (int v = 0; v < 5; ++v) {
    float x = vals[v];
#pragma unroll
    for (int off = 32; off > 0; off >>= 1) x += __shfl_down(x, off);
    vals[v] = x;
  }
  const int wave = t >> 6, lane = t & 63;
  if (lane == 0) {
#pragma unroll
    for (int v = 0; v < 5; ++v) sRed[wave][v] = vals[v];
  }
  __syncthreads();
  if (t == 0) {
#pragma unroll
    for (int v = 0; v < 5; ++v) {
      atomicAdd(&acc[v],
                (double)(sRed[0][v] + sRed[1][v] + sRed[2][v] + sRed[3][v]));
    }
  }
}

__global__ void finalize_kernel(const double* __restrict__ acc, float* __restrict__ out) {
  const double N  = 32.0 * 512.0 * 512.0;
  const double N1 = 32.0 * 256.0 * 256.0;
  const double N2 = 32.0 * 128.0 * 128.0;
  const double N3 = 32.0 * 64.0 * 64.0;
  const double rec  = acc[0] / N;
  const double reg  = acc[1] / N;
  const double lvl1 = acc[2] / (3.0 * N1);
  const double lvl2 = acc[3] / (3.0 * N2);
  const double lvl3 = acc[4] / (3.0 * N3);
  const double total = rec + 2.0 * reg + 0.05 * (lvl1 / 3.0 + lvl2 / 2.0 + lvl3);
  out[0] = (float)total;
}

}  // namespace

extern "C" void kernel_launch(void* const* d_in, const int* in_sizes, int n_in,
                              void* d_out, int out_size, void* d_ws, size_t ws_size,
                              hipStream_t stream) {
  const float* noisy  = (const float*)d_in[0];
  const float* weight = (const float*)d_in[1];
  double* acc = (double*)d_ws;
  float* out  = (float*)d_out;

  hipLaunchKernelGGL(zero_acc_kernel, dim3(1), dim3(64), 0, stream, acc);
  dim3 grid(IMG / 32, IMG / 32, 32);
  hipLaunchKernelGGL(n2n_wavelet_kernel, grid, dim3(256), 0, stream, noisy, weight, acc);
  hipLaunchKernelGGL(finalize_kernel, dim3(1), dim3(1), 0, stream, acc, out);
}

// Round 3
// 104.193 us; speedup vs baseline: 5.4475x; 5.4475x over previous
//
#include <hip/hip_runtime.h>

namespace {

constexpr int   IMG = 512;
constexpr float THR = 50.0f / 255.0f;
constexpr int   NBLOCKS = (IMG / 32) * (IMG / 32) * 32;  // 8192

// Pre-weighted combination constants (the final loss is linear in the 5 sums):
// total = rec/N + 2*reg/N + 0.05*( (w1/(3*N1))/3 + (w2/(3*N2))/2 + w3/(3*N3) )
constexpr double N_PIX = 32.0 * 512.0 * 512.0;   // 8388608
constexpr double N_L1  = 32.0 * 256.0 * 256.0;   // 2097152
constexpr double N_L2  = 32.0 * 128.0 * 128.0;   // 524288
constexpr double N_L3  = 32.0 * 64.0 * 64.0;     // 131072
constexpr double C_REC = 1.0 / N_PIX;
constexpr double C_REG = 2.0 / N_PIX;
constexpr double C_W1  = 0.05 / (9.0 * N_L1);
constexpr double C_W2  = 0.05 / (6.0 * N_L2);
constexpr double C_W3  = 0.05 / (3.0 * N_L3);

// Tile: 32x32 output pixels per block, 256 threads.
// jax.image.resize 'linear' 256->512 closed form (clamped staging makes the
// interior formula exact at boundaries; verified bit-exact R1/R2):
//   even g=2k: 0.25*in[k-1] + 0.75*in[k];  odd g=2k+1: 0.75*in[k] + 0.25*in[k+1]
__global__ __launch_bounds__(256) void n2n_wavelet_kernel(
    const float* __restrict__ noisy,
    const float* __restrict__ weight,
    double* __restrict__ partial) {
  __shared__ float sP0[18][20];   // p0 = noisy[0::2,0::2] window, clamped
  __shared__ float sP3[18][20];   // p3 = noisy[1::2,1::2] window, clamped
  __shared__ float sG1[34][36];   // g1 tile + conv halo (zero outside image)
  __shared__ float sOut[32][36];  // clipped conv output
  __shared__ float sLL1[16][18];
  __shared__ float sLL2[8][10];
  __shared__ float sRed[4][5];

  const int t  = threadIdx.x;
  const int tx = blockIdx.x;
  const int ty = blockIdx.y;
  const int b  = blockIdx.z;
  const float* img = noisy + (size_t)b * IMG * IMG;

  const int py0 = 16 * ty - 1;  // staging origin in p0/p3 index space
  const int px0 = 16 * tx - 1;

  float wk[9];
#pragma unroll
  for (int i = 0; i < 9; ++i) wk[i] = weight[i];

  // ---- Phase A: stage 18x18 p0 and p3 windows (clamped) ----
  {
    const int r = t >> 4, c = t & 15;
    auto stage = [&](int rr, int cc) {
      int gr = py0 + rr; gr = gr < 0 ? 0 : (gr > 255 ? 255 : gr);
      int gc = px0 + cc; gc = gc < 0 ? 0 : (gc > 255 ? 255 : gc);
      sP0[rr][cc] = img[(gr * 2) * IMG + gc * 2];
      sP3[rr][cc] = img[(gr * 2 + 1) * IMG + gc * 2 + 1];
    };
    stage(r, c);
    if (c < 2) stage(r, c + 16);
    if (r < 2) stage(r + 16, c);
    if (r < 2 && c < 2) stage(r + 16, c + 16);
  }
  __syncthreads();

  const int gyb0 = 32 * ty, gxb0 = 32 * tx;

  // ---- Phase B: g1 via 2x2 quads (pair-factored bilinear), 17x17 quads ----
  for (int q = t; q < 289; q += 256) {
    const int n = q / 17;          // compile-time magic mul
    const int m = q - n * 17;
    const float a  = sP0[n][m],     bb = sP0[n][m + 1];
    const float cc = sP0[n + 1][m], dd = sP0[n + 1][m + 1];
    const float xt0 = 0.75f * a + 0.25f * bb;   // local col 2m   (odd gx)
    const float xt1 = 0.25f * a + 0.75f * bb;   // local col 2m+1 (even gx)
    const float xb0 = 0.75f * cc + 0.25f * dd;
    const float xb1 = 0.25f * cc + 0.75f * dd;
    float v00 = 0.75f * xt0 + 0.25f * xb0;      // local row 2n   (odd gy)
    float v01 = 0.75f * xt1 + 0.25f * xb1;
    float v10 = 0.25f * xt0 + 0.75f * xb0;      // local row 2n+1 (even gy)
    float v11 = 0.25f * xt1 + 0.75f * xb1;
    // SAME-pad: zero outside image (only edge tiles hit this)
    const int gyt = gyb0 - 1 + 2 * n, gxl = gxb0 - 1 + 2 * m;
    const bool vt = (unsigned)gyt < (unsigned)IMG, vb = (unsigned)(gyt + 1) < (unsigned)IMG;
    const bool vl = (unsigned)gxl < (unsigned)IMG, vr = (unsigned)(gxl + 1) < (unsigned)IMG;
    v00 = (vt && vl) ? v00 : 0.0f;  v01 = (vt && vr) ? v01 : 0.0f;
    v10 = (vb && vl) ? v10 : 0.0f;  v11 = (vb && vr) ? v11 : 0.0f;
    *(float2*)&sG1[2 * n][2 * m]     = make_float2(v00, v01);
    *(float2*)&sG1[2 * n + 1][2 * m] = make_float2(v10, v11);
  }
  __syncthreads();

  // ---- Phase C: conv3x3 + clip + rec/reg; thread = 1 row x 4 cols ----
  float rec = 0.0f, rgg = 0.0f;
  {
    const int row  = t >> 3;          // 0..31
    const int col0 = (t & 7) << 2;    // 0..28 step 4
    float a0 = 0, a1 = 0, a2 = 0, a3 = 0;
    float g1c0 = 0, g1c1 = 0, g1c2 = 0, g1c3 = 0;
#pragma unroll
    for (int u = 0; u < 3; ++u) {
      const float4 q4 = *(const float4*)&sG1[row + u][col0];      // 16B aligned
      const float2 e2 = *(const float2*)&sG1[row + u][col0 + 4];  // 8B aligned
      const float w0 = wk[3 * u], w1 = wk[3 * u + 1], w2 = wk[3 * u + 2];
      a0 += w0 * q4.x + w1 * q4.y + w2 * q4.z;
      a1 += w0 * q4.y + w1 * q4.z + w2 * q4.w;
      a2 += w0 * q4.z + w1 * q4.w + w2 * e2.x;
      a3 += w0 * q4.w + w1 * e2.x + w2 * e2.y;
      if (u == 1) { g1c0 = q4.y; g1c1 = q4.z; g1c2 = q4.w; g1c3 = e2.x; }
    }
    const float o0 = fminf(fmaxf(a0, 0.0f), 1.0f);
    const float o1 = fminf(fmaxf(a1, 0.0f), 1.0f);
    const float o2 = fminf(fmaxf(a2, 0.0f), 1.0f);
    const float o3 = fminf(fmaxf(a3, 0.0f), 1.0f);
    *(float4*)&sOut[row][col0] = make_float4(o0, o1, o2, o3);

    // g2 taps from sP3
    const int   r0l = (row >> 1) + (row & 1);
    const float wyt = (row & 1) ? 0.75f : 0.25f;
    const float wyb = 1.0f - wyt;
    const int   c0l = col0 >> 1;
    const float2 t01 = *(const float2*)&sP3[r0l][c0l];
    const float2 t23 = *(const float2*)&sP3[r0l][c0l + 2];
    const float2 b01 = *(const float2*)&sP3[r0l + 1][c0l];
    const float2 b23 = *(const float2*)&sP3[r0l + 1][c0l + 2];
    const float xt0 = 0.25f * t01.x + 0.75f * t01.y;
    const float xt1 = 0.75f * t01.y + 0.25f * t23.x;
    const float xt2 = 0.25f * t01.y + 0.75f * t23.x;
    const float xt3 = 0.75f * t23.x + 0.25f * t23.y;
    const float xb0 = 0.25f * b01.x + 0.75f * b01.y;
    const float xb1 = 0.75f * b01.y + 0.25f * b23.x;
    const float xb2 = 0.25f * b01.y + 0.75f * b23.x;
    const float xb3 = 0.75f * b23.x + 0.25f * b23.y;
    const float g20 = wyt * xt0 + wyb * xb0;
    const float g21 = wyt * xt1 + wyb * xb1;
    const float g22 = wyt * xt2 + wyb * xb2;
    const float g23 = wyt * xt3 + wyb * xb3;

    float d;
    d = o0 - g20; rec += d * d;   d = o1 - g21; rec += d * d;
    d = o2 - g22; rec += d * d;   d = o3 - g23; rec += d * d;
    d = o0 - g1c0; rgg += d * d;  d = o1 - g1c1; rgg += d * d;
    d = o2 - g1c2; rgg += d * d;  d = o3 - g1c3; rgg += d * d;
  }
  __syncthreads();

  // ---- Phase D: 3-level Haar ----
  float w1a = 0.0f, w2a = 0.0f, w3a = 0.0f;
  {
    const int i = t >> 4, j = t & 15;   // 16x16: one coeff per thread
    const float2 top = *(const float2*)&sOut[2 * i][2 * j];
    const float2 bot = *(const float2*)&sOut[2 * i + 1][2 * j];
    const float aa = top.x, bb = top.y, cc = bot.x, dd = bot.y;
    sLL1[i][j] = (aa + bb + cc + dd) * 0.5f;
    const float lh = (aa - bb + cc - dd) * 0.5f;
    const float hl = (aa + bb - cc - dd) * 0.5f;
    const float hh = (aa - bb - cc + dd) * 0.5f;
    const float th = THR * 0.25f;
    w1a = fminf(fabsf(lh), th) + fminf(fabsf(hl), th) + fminf(fabsf(hh), th);
  }
  __syncthreads();
  if (t < 64) {
    const int i = t >> 3, j = t & 7;    // 8x8
    const float2 top = *(const float2*)&sLL1[2 * i][2 * j];
    const float2 bot = *(const float2*)&sLL1[2 * i + 1][2 * j];
    const float aa = top.x, bb = top.y, cc = bot.x, dd = bot.y;
    sLL2[i][j] = (aa + bb + cc + dd) * 0.5f;
    const float lh = (aa - bb + cc - dd) * 0.5f;
    const float hl = (aa + bb - cc - dd) * 0.5f;
    const float hh = (aa - bb - cc + dd) * 0.5f;
    const float th = THR * 0.5f;
    w2a = fminf(fabsf(lh), th) + fminf(fabsf(hl), th) + fminf(fabsf(hh), th);
  }
  __syncthreads();
  if (t < 16) {
    const int i = t >> 2, j = t & 3;    // 4x4
    const float2 top = *(const float2*)&sLL2[2 * i][2 * j];
    const float2 bot = *(const float2*)&sLL2[2 * i + 1][2 * j];
    const float aa = top.x, bb = top.y, cc = bot.x, dd = bot.y;
    const float lh = (aa - bb + cc - dd) * 0.5f;
    const float hl = (aa + bb - cc - dd) * 0.5f;
    const float hh = (aa - bb - cc + dd) * 0.5f;
    w3a = fminf(fabsf(lh), THR) + fminf(fabsf(hl), THR) + fminf(fabsf(hh), THR);
  }

  // ---- Block reduce 5 sums -> ONE pre-weighted double, plain store ----
  float vals[5] = {rec, rgg, w1a, w2a, w3a};
#pragma unroll
  for (int v = 0; v < 5; ++v) {
    float x = vals[v];
#pragma unroll
    for (int off = 32; off > 0; off >>= 1) x += __shfl_down(x, off);
    vals[v] = x;
  }
  const int wave = t >> 6, lane = t & 63;
  if (lane == 0) {
#pragma unroll
    for (int v = 0; v < 5; ++v) sRed[wave][v] = vals[v];
  }
  __syncthreads();
  if (t == 0) {
    double s[5];
#pragma unroll
    for (int v = 0; v < 5; ++v)
      s[v] = (double)(sRed[0][v] + sRed[1][v] + sRed[2][v] + sRed[3][v]);
    const double contrib =
        C_REC * s[0] + C_REG * s[1] + C_W1 * s[2] + C_W2 * s[3] + C_W3 * s[4];
    const int bid = (blockIdx.z * gridDim.y + blockIdx.y) * gridDim.x + blockIdx.x;
    partial[bid] = contrib;  // plain store, no contention
  }
}

__global__ __launch_bounds__(256) void finalize_kernel(
    const double* __restrict__ partial, float* __restrict__ out) {
  __shared__ double sRed[4];
  const int t = threadIdx.x;
  double s = 0.0;
  for (int i = t; i < NBLOCKS; i += 256) s += partial[i];
#pragma unroll
  for (int off = 32; off > 0; off >>= 1) s += __shfl_down(s, off);
  if ((t & 63) == 0) sRed[t >> 6] = s;
  __syncthreads();
  if (t == 0) out[0] = (float)(sRed[0] + sRed[1] + sRed[2] + sRed[3]);
}

}  // namespace

extern "C" void kernel_launch(void* const* d_in, const int* in_sizes, int n_in,
                              void* d_out, int out_size, void* d_ws, size_t ws_size,
                              hipStream_t stream) {
  const float* noisy  = (const float*)d_in[0];
  const float* weight = (const float*)d_in[1];
  double* partial = (double*)d_ws;   // NBLOCKS doubles = 64 KB
  float* out = (float*)d_out;

  dim3 grid(IMG / 32, IMG / 32, 32);
  hipLaunchKernelGGL(n2n_wavelet_kernel, grid, dim3(256), 0, stream, noisy, weight, partial);
  hipLaunchKernelGGL(finalize_kernel, dim3(1), dim3(256), 0, stream, partial, out);
}

// Round 4
// 85.247 us; speedup vs baseline: 6.6581x; 1.2222x over previous
//
#include <hip/hip_runtime.h>

namespace {

constexpr int IMG = 512;
constexpr int S = 8;                    // output rows per wave
constexpr int NSTRIPS = IMG / S;        // 64
constexpr int NWAVES = 32 * NSTRIPS;    // 2048
constexpr int NBLK = NWAVES / 4;        // 512 blocks of 4 waves
constexpr float THR = 50.0f / 255.0f;

// Final loss is linear in the 5 raw sums; pre-weight per wave.
constexpr double N_PIX = 32.0 * 512.0 * 512.0;
constexpr double N_L1  = 32.0 * 256.0 * 256.0;
constexpr double N_L2  = 32.0 * 128.0 * 128.0;
constexpr double N_L3  = 32.0 * 64.0 * 64.0;
constexpr double C_REC = 1.0 / N_PIX;
constexpr double C_REG = 2.0 / N_PIX;
constexpr double C_W1  = 0.05 / (9.0 * N_L1);
constexpr double C_W2  = 0.05 / (6.0 * N_L2);
constexpr double C_W3  = 0.05 / (3.0 * N_L3);

struct F4 { float v[4]; };
struct F8 { float v[8]; };
struct Row { F8 g; float gl, gr; };     // 8 cols + pre-shuffled zero-pad halos

// Lane L covers image cols [8L, 8L+8). Even cols -> p0-phase, odd -> p3-phase.
__device__ __forceinline__ F4 load_even_cols(const float* rowp) {
  const float4 lo = *(const float4*)rowp;
  const float4 hi = *(const float4*)(rowp + 4);
  F4 r; r.v[0] = lo.x; r.v[1] = lo.z; r.v[2] = hi.x; r.v[3] = hi.z; return r;
}
__device__ __forceinline__ F4 load_odd_cols(const float* rowp) {
  const float4 lo = *(const float4*)rowp;
  const float4 hi = *(const float4*)(rowp + 4);
  F4 r; r.v[0] = lo.y; r.v[1] = lo.w; r.v[2] = hi.y; r.v[3] = hi.w; return r;
}

// Horizontal resize blend: 4 phase values (cols j=4L..4L+3) -> 8 upsampled cols.
// jax.image.resize 'linear' 256->512: even g=2j: 0.25*in[j-1]+0.75*in[j];
// odd g=2j+1: 0.75*in[j]+0.25*in[j+1]; index-clamped (boundary-equivalent, R1-verified).
__device__ __forceinline__ F8 hblend(const F4& p, int lane) {
  float left  = __shfl_up(p.v[3], 1);
  float right = __shfl_down(p.v[0], 1);
  if (lane == 0)  left  = p.v[0];
  if (lane == 63) right = p.v[3];
  F8 h;
  h.v[0] = 0.25f*left   + 0.75f*p.v[0];
  h.v[1] = 0.75f*p.v[0] + 0.25f*p.v[1];
  h.v[2] = 0.25f*p.v[0] + 0.75f*p.v[1];
  h.v[3] = 0.75f*p.v[1] + 0.25f*p.v[2];
  h.v[4] = 0.25f*p.v[1] + 0.75f*p.v[2];
  h.v[5] = 0.75f*p.v[2] + 0.25f*p.v[3];
  h.v[6] = 0.25f*p.v[2] + 0.75f*p.v[3];
  h.v[7] = 0.75f*p.v[3] + 0.25f*right;
  return h;
}

// Vertical resize blend -> one g1 row, with conv zero-pad halos pre-shuffled.
__device__ __forceinline__ Row vblend(const F8& a, const F8& b, float wa, float wb, int lane) {
  Row r;
#pragma unroll
  for (int c = 0; c < 8; ++c) r.g.v[c] = wa*a.v[c] + wb*b.v[c];
  const float gl = __shfl_up(r.g.v[7], 1);
  const float gr = __shfl_down(r.g.v[0], 1);
  r.gl = (lane == 0)  ? 0.0f : gl;
  r.gr = (lane == 63) ? 0.0f : gr;
  return r;
}

__device__ __forceinline__ void conv_acc(const Row& r, const float* wk3, F8& acc) {
#pragma unroll
  for (int c = 0; c < 8; ++c) {
    const float gm1 = (c == 0) ? r.gl : r.g.v[c-1];
    const float gp1 = (c == 7) ? r.gr : r.g.v[c+1];
    acc.v[c] += wk3[0]*gm1 + wk3[1]*r.g.v[c] + wk3[2]*gp1;
  }
}

__device__ __forceinline__ F8 conv3(const Row& r0, const Row& r1, const Row& r2,
                                    const float* wk) {
  F8 o;
#pragma unroll
  for (int c = 0; c < 8; ++c) o.v[c] = 0.0f;
  conv_acc(r0, wk + 0, o);
  conv_acc(r1, wk + 3, o);
  conv_acc(r2, wk + 6, o);
#pragma unroll
  for (int c = 0; c < 8; ++c) o.v[c] = fminf(fmaxf(o.v[c], 0.0f), 1.0f);
  return o;
}

__device__ __forceinline__ F4 haarL1(const F8& e, const F8& o, float thr, float& acc) {
  F4 ll;
#pragma unroll
  for (int c = 0; c < 4; ++c) {
    const float a = e.v[2*c], b = e.v[2*c+1], cc = o.v[2*c], d = o.v[2*c+1];
    ll.v[c] = (a + b + cc + d) * 0.5f;
    const float lh = (a - b + cc - d) * 0.5f;
    const float hl = (a + b - cc - d) * 0.5f;
    const float hh = (a - b - cc + d) * 0.5f;
    acc += fminf(fabsf(lh), thr) + fminf(fabsf(hl), thr) + fminf(fabsf(hh), thr);
  }
  return ll;
}

__device__ __forceinline__ float haar1pair(float a, float b, float cc, float d,
                                           float thr, float& acc) {
  const float lh = (a - b + cc - d) * 0.5f;
  const float hl = (a + b - cc - d) * 0.5f;
  const float hh = (a - b - cc + d) * 0.5f;
  acc += fminf(fabsf(lh), thr) + fminf(fabsf(hl), thr) + fminf(fabsf(hh), thr);
  return (a + b + cc + d) * 0.5f;
}

__global__ __launch_bounds__(256, 2) void n2n_wavelet_kernel(
    const float* __restrict__ noisy,
    const float* __restrict__ weight,
    double* __restrict__ partial) {
  const int t = threadIdx.x;
  const int lane = t & 63;
  const int gwid = blockIdx.x * 4 + (t >> 6);
  const int strip = gwid & (NSTRIPS - 1);
  const int b = gwid >> 6;
  const float* base = noisy + (size_t)b * IMG * IMG + lane * 8;

  const int y0 = strip * S;
  const int k0 = y0 >> 1;                 // phase-row index of first pair
  const bool lastStrip = (y0 == IMG - S);

  float wk[9];
#pragma unroll
  for (int i = 0; i < 9; ++i) wk[i] = weight[i];

  float rec = 0.f, rgg = 0.f, w1a = 0.f, w2a = 0.f, w3a = 0.f;
  const float thr1 = THR * 0.25f, thr2 = THR * 0.5f;

  // ---- Prologue: h rows k0-1, k0 for p0/p3; g1 rows y0-1, y0 ----
  const int r0e = (k0 > 0) ? 2*(k0 - 1) : 0;     // clamped img row of p0[k0-1]
  const F4 p0m = load_even_cols(base + r0e * IMG);
  const F4 p0c = load_even_cols(base + (2*k0) * IMG);
  const F4 p3m = load_odd_cols(base + (r0e + 1) * IMG);
  const F4 p3c = load_odd_cols(base + (2*k0 + 1) * IMG);
  const F8 hKm1 = hblend(p0m, lane);
  F8 hCur  = hblend(p0c, lane);
  F8 h3Prev = hblend(p3m, lane);
  F8 h3Cur  = hblend(p3c, lane);

  Row g1m, g1c;
  if (y0 == 0) {                                  // SAME conv zero-pad row -1
#pragma unroll
    for (int c = 0; c < 8; ++c) g1m.g.v[c] = 0.f;
    g1m.gl = 0.f; g1m.gr = 0.f;
  } else {
    g1m = vblend(hKm1, hCur, 0.75f, 0.25f, lane); // g1[y0-1] (odd row)
  }
  g1c = vblend(hKm1, hCur, 0.25f, 0.75f, lane);   // g1[y0]   (even row)

  F4 ll1Prev;
  float ll2Prev0 = 0.f, ll2Prev1 = 0.f;

#pragma unroll
  for (int p = 0; p < 4; ++p) {
    const int k = k0 + p;
    const int nr0 = (k < 255) ? 2*(k + 1) : 510;  // clamped img rows for k+1
    const F4 p0n = load_even_cols(base + nr0 * IMG);
    const F4 p3n = load_odd_cols(base + (nr0 + 1) * IMG);

    const F8 hN = hblend(p0n, lane);
    const Row g1p = vblend(hCur, hN, 0.75f, 0.25f, lane);  // g1[2k+1]

    // out row 2k (even)
    const F8 outE = conv3(g1m, g1c, g1p, wk);
#pragma unroll
    for (int c = 0; c < 8; ++c) {
      const float g2 = 0.25f*h3Prev.v[c] + 0.75f*h3Cur.v[c];
      float d = outE.v[c] - g2;        rec += d*d;
      d = outE.v[c] - g1c.g.v[c];      rgg += d*d;
    }

    Row g1q = vblend(hCur, hN, 0.25f, 0.75f, lane);        // g1[2k+2]
    if (lastStrip && p == 3) {                             // g1[512] = zero pad
#pragma unroll
      for (int c = 0; c < 8; ++c) g1q.g.v[c] = 0.f;
      g1q.gl = 0.f; g1q.gr = 0.f;
    }
    const F8 h3N = hblend(p3n, lane);

    // out row 2k+1 (odd)
    const F8 outO = conv3(g1c, g1p, g1q, wk);
#pragma unroll
    for (int c = 0; c < 8; ++c) {
      const float g2 = 0.75f*h3Cur.v[c] + 0.25f*h3N.v[c];
      float d = outO.v[c] - g2;        rec += d*d;
      d = outO.v[c] - g1p.g.v[c];      rgg += d*d;
    }

    // Haar level 1 (rows 2k,2k+1; col pairs lane-local)
    const F4 ll1 = haarL1(outE, outO, thr1, w1a);
    if ((p & 1) == 0) {
      ll1Prev = ll1;
    } else {
      const float ll20 = haar1pair(ll1Prev.v[0], ll1Prev.v[1], ll1.v[0], ll1.v[1], thr2, w2a);
      const float ll21 = haar1pair(ll1Prev.v[2], ll1Prev.v[3], ll1.v[2], ll1.v[3], thr2, w2a);
      if (p == 1) {
        ll2Prev0 = ll20; ll2Prev1 = ll21;
      } else {
        const float lh = (ll2Prev0 - ll2Prev1 + ll20 - ll21) * 0.5f;
        const float hl = (ll2Prev0 + ll2Prev1 - ll20 - ll21) * 0.5f;
        const float hh = (ll2Prev0 - ll2Prev1 - ll20 + ll21) * 0.5f;
        w3a += fminf(fabsf(lh), THR) + fminf(fabsf(hl), THR) + fminf(fabsf(hh), THR);
      }
    }

    // rotate register rings
    g1m = g1p; g1c = g1q; hCur = hN; h3Prev = h3Cur; h3Cur = h3N;
  }

  // ---- Wave reduce -> one pre-weighted double per wave, plain store ----
  float vals[5] = {rec, rgg, w1a, w2a, w3a};
#pragma unroll
  for (int v = 0; v < 5; ++v) {
#pragma unroll
    for (int off = 32; off > 0; off >>= 1) vals[v] += __shfl_down(vals[v], off);
  }
  if (lane == 0) {
    partial[gwid] = C_REC*(double)vals[0] + C_REG*(double)vals[1]
                  + C_W1*(double)vals[2] + C_W2*(double)vals[3] + C_W3*(double)vals[4];
  }
}

__global__ __launch_bounds__(256) void finalize_kernel(
    const double* __restrict__ partial, float* __restrict__ out) {
  __shared__ double sRed[4];
  const int t = threadIdx.x;
  double s = 0.0;
#pragma unroll
  for (int i = 0; i < NWAVES / 256; ++i) s += partial[i * 256 + t];
#pragma unroll
  for (int off = 32; off > 0; off >>= 1) s += __shfl_down(s, off);
  if ((t & 63) == 0) sRed[t >> 6] = s;
  __syncthreads();
  if (t == 0) out[0] = (float)(sRed[0] + sRed[1] + sRed[2] + sRed[3]);
}

}  // namespace

extern "C" void kernel_launch(void* const* d_in, const int* in_sizes, int n_in,
                              void* d_out, int out_size, void* d_ws, size_t ws_size,
                              hipStream_t stream) {
  const float* noisy  = (const float*)d_in[0];
  const float* weight = (const float*)d_in[1];
  double* partial = (double*)d_ws;   // NWAVES doubles = 16 KB
  float* out = (float*)d_out;

  hipLaunchKernelGGL(n2n_wavelet_kernel, dim3(NBLK), dim3(256), 0, stream,
                     noisy, weight, partial);
  hipLaunchKernelGGL(finalize_kernel, dim3(1), dim3(256), 0, stream, partial, out);
}

// Round 5
// 83.654 us; speedup vs baseline: 6.7849x; 1.0190x over previous
//
#include <hip/hip_runtime.h>

namespace {

constexpr int IMG = 512;
constexpr int S = 8;                    // output rows per wave
constexpr int NSTRIPS = IMG / S;        // 64
constexpr int NWAVES = 32 * NSTRIPS;    // 2048
constexpr int NBLK = NWAVES / 4;        // 512 blocks of 4 waves
constexpr float THR = 50.0f / 255.0f;

// Final loss is linear in the 5 raw sums; pre-weight per wave.
constexpr double N_PIX = 32.0 * 512.0 * 512.0;
constexpr double N_L1  = 32.0 * 256.0 * 256.0;
constexpr double N_L2  = 32.0 * 128.0 * 128.0;
constexpr double N_L3  = 32.0 * 64.0 * 64.0;
constexpr double C_REC = 1.0 / N_PIX;
constexpr double C_REG = 2.0 / N_PIX;
constexpr double C_W1  = 0.05 / (9.0 * N_L1);
constexpr double C_W2  = 0.05 / (6.0 * N_L2);
constexpr double C_W3  = 0.05 / (3.0 * N_L3);

struct F4 { float v[4]; };
struct F8 { float v[8]; };
struct Row { F8 g; float gl, gr; };     // 8 cols + pre-shuffled zero-pad halos

// Horizontal resize blend: 4 phase values (cols j=4L..4L+3) -> 8 upsampled cols.
// jax.image.resize 'linear' 256->512: even g=2j: 0.25*in[j-1]+0.75*in[j];
// odd g=2j+1: 0.75*in[j]+0.25*in[j+1]; index-clamped (bit-exact R1-R4).
__device__ __forceinline__ F8 hblend(const F4& p, int lane) {
  float left  = __shfl_up(p.v[3], 1);
  float right = __shfl_down(p.v[0], 1);
  if (lane == 0)  left  = p.v[0];
  if (lane == 63) right = p.v[3];
  F8 h;
  h.v[0] = 0.25f*left   + 0.75f*p.v[0];
  h.v[1] = 0.75f*p.v[0] + 0.25f*p.v[1];
  h.v[2] = 0.25f*p.v[0] + 0.75f*p.v[1];
  h.v[3] = 0.75f*p.v[1] + 0.25f*p.v[2];
  h.v[4] = 0.25f*p.v[1] + 0.75f*p.v[2];
  h.v[5] = 0.75f*p.v[2] + 0.25f*p.v[3];
  h.v[6] = 0.25f*p.v[2] + 0.75f*p.v[3];
  h.v[7] = 0.75f*p.v[3] + 0.25f*right;
  return h;
}

// Vertical resize blend -> one g1 row, with conv zero-pad halos pre-shuffled.
__device__ __forceinline__ Row vblend(const F8& a, const F8& b, float wa, float wb, int lane) {
  Row r;
#pragma unroll
  for (int c = 0; c < 8; ++c) r.g.v[c] = wa*a.v[c] + wb*b.v[c];
  const float gl = __shfl_up(r.g.v[7], 1);
  const float gr = __shfl_down(r.g.v[0], 1);
  r.gl = (lane == 0)  ? 0.0f : gl;
  r.gr = (lane == 63) ? 0.0f : gr;
  return r;
}

__device__ __forceinline__ void conv_acc(const Row& r, const float* wk3, F8& acc) {
#pragma unroll
  for (int c = 0; c < 8; ++c) {
    const float gm1 = (c == 0) ? r.gl : r.g.v[c-1];
    const float gp1 = (c == 7) ? r.gr : r.g.v[c+1];
    acc.v[c] += wk3[0]*gm1 + wk3[1]*r.g.v[c] + wk3[2]*gp1;
  }
}

__device__ __forceinline__ F8 conv3(const Row& r0, const Row& r1, const Row& r2,
                                    const float* wk) {
  F8 o;
#pragma unroll
  for (int c = 0; c < 8; ++c) o.v[c] = 0.0f;
  conv_acc(r0, wk + 0, o);
  conv_acc(r1, wk + 3, o);
  conv_acc(r2, wk + 6, o);
#pragma unroll
  for (int c = 0; c < 8; ++c) o.v[c] = fminf(fmaxf(o.v[c], 0.0f), 1.0f);
  return o;
}

__device__ __forceinline__ F4 haarL1(const F8& e, const F8& o, float thr, float& acc) {
  F4 ll;
#pragma unroll
  for (int c = 0; c < 4; ++c) {
    const float a = e.v[2*c], b = e.v[2*c+1], cc = o.v[2*c], d = o.v[2*c+1];
    ll.v[c] = (a + b + cc + d) * 0.5f;
    const float lh = (a - b + cc - d) * 0.5f;
    const float hl = (a + b - cc - d) * 0.5f;
    const float hh = (a - b - cc + d) * 0.5f;
    acc += fminf(fabsf(lh), thr) + fminf(fabsf(hl), thr) + fminf(fabsf(hh), thr);
  }
  return ll;
}

__device__ __forceinline__ float haar1pair(float a, float b, float cc, float d,
                                           float thr, float& acc) {
  const float lh = (a - b + cc - d) * 0.5f;
  const float hl = (a + b - cc - d) * 0.5f;
  const float hh = (a - b - cc + d) * 0.5f;
  acc += fminf(fabsf(lh), thr) + fminf(fabsf(hl), thr) + fminf(fabsf(hh), thr);
  return (a + b + cc + d) * 0.5f;
}

__global__ __launch_bounds__(256, 2) void n2n_wavelet_kernel(
    const float* __restrict__ noisy,
    const float* __restrict__ weight,
    double* __restrict__ partial) {
  const int t = threadIdx.x;
  const int lane = t & 63;
  const int gwid = blockIdx.x * 4 + (t >> 6);
  const int strip = gwid & (NSTRIPS - 1);
  const int b = gwid >> 6;
  const float* base = noisy + (size_t)b * IMG * IMG + lane * 8;

  const int y0 = strip * S;
  const int k0 = y0 >> 1;                 // phase-row index of first pair
  const bool lastStrip = (y0 == IMG - S);

  // ---- Hoist ALL 24 dwordx4 loads: phase rows k0-1 .. k0+4 (clamped) ----
  float4 le0[6], le1[6], lo0[6], lo1[6];
#pragma unroll
  for (int i = 0; i < 6; ++i) {
    int r = k0 - 1 + i;
    r = r < 0 ? 0 : (r > 255 ? 255 : r);
    const float* pe = base + (2 * r) * IMG;       // even image row (p0 phase)
    const float* po = base + (2 * r + 1) * IMG;   // odd image row (p3 phase)
    le0[i] = *(const float4*)pe;
    le1[i] = *(const float4*)(pe + 4);
    lo0[i] = *(const float4*)po;
    lo1[i] = *(const float4*)(po + 4);
  }

  float wk[9];
#pragma unroll
  for (int i = 0; i < 9; ++i) wk[i] = weight[i];

  // ---- Extract checkerboard phases + horizontal blends (consume in order) ----
  F8 h0[6], h3[6];
#pragma unroll
  for (int i = 0; i < 6; ++i) {
    F4 e, o;
    e.v[0] = le0[i].x; e.v[1] = le0[i].z; e.v[2] = le1[i].x; e.v[3] = le1[i].z;
    o.v[0] = lo0[i].y; o.v[1] = lo0[i].w; o.v[2] = lo1[i].y; o.v[3] = lo1[i].w;
    h0[i] = hblend(e, lane);
    h3[i] = hblend(o, lane);
  }

  float rec = 0.f, rgg = 0.f, w1a = 0.f, w2a = 0.f, w3a = 0.f;
  const float thr1 = THR * 0.25f, thr2 = THR * 0.5f;

  // ---- g1 prologue rows y0-1 (odd), y0 (even) ----
  Row g1m, g1c;
  if (y0 == 0) {                                  // SAME conv zero-pad row -1
#pragma unroll
    for (int c = 0; c < 8; ++c) g1m.g.v[c] = 0.f;
    g1m.gl = 0.f; g1m.gr = 0.f;
  } else {
    g1m = vblend(h0[0], h0[1], 0.75f, 0.25f, lane);
  }
  g1c = vblend(h0[0], h0[1], 0.25f, 0.75f, lane);

  F4 ll1Prev;
  float ll2Prev0 = 0.f, ll2Prev1 = 0.f;

#pragma unroll
  for (int p = 0; p < 4; ++p) {
    const Row g1p = vblend(h0[p + 1], h0[p + 2], 0.75f, 0.25f, lane);  // g1[2k+1]

    // out row 2k (even)
    const F8 outE = conv3(g1m, g1c, g1p, wk);
#pragma unroll
    for (int c = 0; c < 8; ++c) {
      const float g2 = 0.25f * h3[p].v[c] + 0.75f * h3[p + 1].v[c];
      float d = outE.v[c] - g2;        rec += d*d;
      d = outE.v[c] - g1c.g.v[c];      rgg += d*d;
    }

    Row g1q = vblend(h0[p + 1], h0[p + 2], 0.25f, 0.75f, lane);        // g1[2k+2]
    if (lastStrip && p == 3) {                                         // g1[512]=0
#pragma unroll
      for (int c = 0; c < 8; ++c) g1q.g.v[c] = 0.f;
      g1q.gl = 0.f; g1q.gr = 0.f;
    }

    // out row 2k+1 (odd)
    const F8 outO = conv3(g1c, g1p, g1q, wk);
#pragma unroll
    for (int c = 0; c < 8; ++c) {
      const float g2 = 0.75f * h3[p + 1].v[c] + 0.25f * h3[p + 2].v[c];
      float d = outO.v[c] - g2;        rec += d*d;
      d = outO.v[c] - g1p.g.v[c];      rgg += d*d;
    }

    // Haar level 1 (rows 2k,2k+1; col pairs lane-local)
    const F4 ll1 = haarL1(outE, outO, thr1, w1a);
    if ((p & 1) == 0) {
      ll1Prev = ll1;
    } else {
      const float ll20 = haar1pair(ll1Prev.v[0], ll1Prev.v[1], ll1.v[0], ll1.v[1], thr2, w2a);
      const float ll21 = haar1pair(ll1Prev.v[2], ll1Prev.v[3], ll1.v[2], ll1.v[3], thr2, w2a);
      if (p == 1) {
        ll2Prev0 = ll20; ll2Prev1 = ll21;
      } else {
        const float lh = (ll2Prev0 - ll2Prev1 + ll20 - ll21) * 0.5f;
        const float hl = (ll2Prev0 + ll2Prev1 - ll20 - ll21) * 0.5f;
        const float hh = (ll2Prev0 - ll2Prev1 - ll20 + ll21) * 0.5f;
        w3a += fminf(fabsf(lh), THR) + fminf(fabsf(hl), THR) + fminf(fabsf(hh), THR);
      }
    }

    g1m = g1p; g1c = g1q;
  }

  // ---- Wave reduce -> one pre-weighted double per wave, plain store ----
  float vals[5] = {rec, rgg, w1a, w2a, w3a};
#pragma unroll
  for (int v = 0; v < 5; ++v) {
#pragma unroll
    for (int off = 32; off > 0; off >>= 1) vals[v] += __shfl_down(vals[v], off);
  }
  if (lane == 0) {
    partial[gwid] = C_REC*(double)vals[0] + C_REG*(double)vals[1]
                  + C_W1*(double)vals[2] + C_W2*(double)vals[3] + C_W3*(double)vals[4];
  }
}

__global__ __launch_bounds__(256) void finalize_kernel(
    const double* __restrict__ partial, float* __restrict__ out) {
  __shared__ double sRed[4];
  const int t = threadIdx.x;
  double s = 0.0;
#pragma unroll
  for (int i = 0; i < NWAVES / 256; ++i) s += partial[i * 256 + t];
#pragma unroll
  for (int off = 32; off > 0; off >>= 1) s += __shfl_down(s, off);
  if ((t & 63) == 0) sRed[t >> 6] = s;
  __syncthreads();
  if (t == 0) out[0] = (float)(sRed[0] + sRed[1] + sRed[2] + sRed[3]);
}

}  // namespace

extern "C" void kernel_launch(void* const* d_in, const int* in_sizes, int n_in,
                              void* d_out, int out_size, void* d_ws, size_t ws_size,
                              hipStream_t stream) {
  const float* noisy  = (const float*)d_in[0];
  const float* weight = (const float*)d_in[1];
  double* partial = (double*)d_ws;   // NWAVES doubles = 16 KB
  float* out = (float*)d_out;

  hipLaunchKernelGGL(n2n_wavelet_kernel, dim3(NBLK), dim3(256), 0, stream,
                     noisy, weight, partial);
  hipLaunchKernelGGL(finalize_kernel, dim3(1), dim3(256), 0, stream, partial, out);
}